// Round 5
// baseline (994.431 us; speedup 1.0000x reference)
//
#include <hip/hip_runtime.h>
#include <hip/hip_bf16.h>

// ---------------------------------------------------------------------------
// KalmanVAE: B=256, S=512, D=64, L=64, HID=256
// out = [x_recon | z_mean | z_logvar], each 131072*64 fp32
//
// z_up_t = M z_{t-1} + c_t,  M = (I-K Hm) A,  c_t = G z_t + K x_t, G = I-K Hm
// Kernels:
//   ktr   : 20 blocks, bf16 transposed weight copies.
//   kenc1 : encoder GEMMs + reparam -> zstg bf16 (out region 0), zmean/zlogv.
//   kmc   : 1 block, matrix chain (no-pivot reg-resident GJ) -- standalone to
//           isolate the round-4 cohabitation regression.
//   kenc2 : c = z@G^T + x@K^T -> cbuf bf16 + phase-A chunk scans -> Pbuf.
//   kchain: per-batch chunk prefix with M^16 (prefetched).
//   kdec  : phase-C chunk scans -> decoder GEMMs -> x_recon.
// ---------------------------------------------------------------------------

typedef short short8 __attribute__((ext_vector_type(8)));
typedef float f32x4 __attribute__((ext_vector_type(4)));

#define OUTSEG 8388608   // 131072*64

__device__ __forceinline__ unsigned short f2bf(float f) {
    unsigned int u = __builtin_bit_cast(unsigned int, f);
    u += 0x7fffu + ((u >> 16) & 1u);   // RNE
    return (unsigned short)(u >> 16);
}
__device__ __forceinline__ float bf2f(unsigned short h) {
    unsigned int u = ((unsigned int)h) << 16;
    return __builtin_bit_cast(float, u);
}
__device__ __forceinline__ float rlf(float v, int l) {
    return __builtin_bit_cast(float, __builtin_amdgcn_readlane(__builtin_bit_cast(int, v), l));
}
// z_new[j] = c[j] + sum_k m[k] * z[k]   (m = row j of M, one wave, no barriers)
__device__ __forceinline__ float matvec_rl(const float* m, float z, float c) {
    float a0 = c, a1 = 0.f, a2 = 0.f, a3 = 0.f;
#pragma unroll
    for (int k = 0; k < 64; k += 4) {
        a0 = fmaf(m[k + 0], rlf(z, k + 0), a0);
        a1 = fmaf(m[k + 1], rlf(z, k + 1), a1);
        a2 = fmaf(m[k + 2], rlf(z, k + 2), a2);
        a3 = fmaf(m[k + 3], rlf(z, k + 3), a3);
    }
    return (a0 + a1) + (a2 + a3);
}
__device__ __forceinline__ void load_mrow(const float* Mp, int j, float* m) {
#pragma unroll
    for (int q = 0; q < 16; q++) {
        float4 v = *reinterpret_cast<const float4*>(&Mp[j * 64 + q * 4]);
        m[q * 4 + 0] = v.x; m[q * 4 + 1] = v.y;
        m[q * 4 + 2] = v.z; m[q * 4 + 3] = v.w;
    }
}

// ---------------------------------------------------------------------------
// ktr : weight transposes (bf16), 20 blocks x 256 threads
// ---------------------------------------------------------------------------
__device__ void tr_tile(const float* src, int sld, unsigned short* dst, int dld,
                        int r0, int c0, int tid, float* LT) {
    int rr = tid >> 2, q = tid & 3;
#pragma unroll
    for (int u = 0; u < 4; u++) {
        float4 v = *reinterpret_cast<const float4*>(
            &src[(size_t)(r0 + rr) * sld + c0 + q * 16 + u * 4]);
        LT[rr * 65 + q * 16 + u * 4 + 0] = v.x;
        LT[rr * 65 + q * 16 + u * 4 + 1] = v.y;
        LT[rr * 65 + q * 16 + u * 4 + 2] = v.z;
        LT[rr * 65 + q * 16 + u * 4 + 3] = v.w;
    }
    __syncthreads();
    short8 s0, s1;
#pragma unroll
    for (int u = 0; u < 8; u++) s0[u] = (short)f2bf(LT[(q * 16 + u) * 65 + rr]);
#pragma unroll
    for (int u = 0; u < 8; u++) s1[u] = (short)f2bf(LT[(q * 16 + 8 + u) * 65 + rr]);
    *reinterpret_cast<short8*>(&dst[(size_t)(c0 + rr) * dld + r0 + q * 16]) = s0;
    *reinterpret_cast<short8*>(&dst[(size_t)(c0 + rr) * dld + r0 + q * 16 + 8]) = s1;
}

__global__ __launch_bounds__(256) void ktr(
    const float* __restrict__ ew1, const float* __restrict__ ew2,
    const float* __restrict__ dw1, const float* __restrict__ dw2,
    unsigned short* __restrict__ w1t, unsigned short* __restrict__ w2t,
    unsigned short* __restrict__ d1t, unsigned short* __restrict__ d2t) {
    __shared__ float La[64 * 65];
    int tid = threadIdx.x;
    int t = blockIdx.x;
    const float* src; unsigned short* dst; int sld, dld, r0, c0;
    if (t < 4)       { src = ew1; dst = w1t; sld = 256; dld = 64;  r0 = 0;             c0 = t * 64; }
    else if (t < 12) { int i = t - 4;  src = ew2; dst = w2t; sld = 128; dld = 256; r0 = (i >> 1) * 64; c0 = (i & 1) * 64; }
    else if (t < 16) { int i = t - 12; src = dw1; dst = d1t; sld = 256; dld = 64;  r0 = 0;             c0 = i * 64; }
    else             { int i = t - 16; src = dw2; dst = d2t; sld = 64;  dld = 256; r0 = i * 64;        c0 = 0; }
    tr_tile(src, sld, dst, dld, r0, c0, tid, La);
}

// ---------------------------------------------------------------------------
// matrix chain (standalone kernel kmc)
// ---------------------------------------------------------------------------
// C = A@B (0) ; C = A@B + D (1) ; C = I - A@B (2).  A,D,C global; B staged->Lx.
// Lx pitch 68 floats (16B-aligned rows). 256 threads.
__device__ __noinline__ void mmc(const float* Ag, const float* Bg, float* Cg,
                                 float* Lx, int mode, const float* Dg,
                                 unsigned short* Cb, int tid) {
    for (int idx = tid; idx < 4096; idx += 256)
        Lx[(idx >> 6) * 68 + (idx & 63)] = Bg[idx];
    __syncthreads();
    int i = tid & 63, j0 = (tid >> 6) * 16;
    float4 a4[16];
#pragma unroll
    for (int q = 0; q < 16; q++)
        a4[q] = reinterpret_cast<const float4*>(Ag + i * 64)[q];
    float acc[16];
#pragma unroll
    for (int jj = 0; jj < 16; jj++) acc[jj] = 0.f;
#pragma unroll
    for (int q = 0; q < 16; q++) {
        float av[4] = {a4[q].x, a4[q].y, a4[q].z, a4[q].w};
#pragma unroll
        for (int t = 0; t < 4; t++) {
            int k = q * 4 + t;
            const float4* Br = reinterpret_cast<const float4*>(&Lx[k * 68 + j0]);
            float4 b0 = Br[0], b1 = Br[1], b2 = Br[2], b3 = Br[3];
            acc[0]  = fmaf(av[t], b0.x, acc[0]);
            acc[1]  = fmaf(av[t], b0.y, acc[1]);
            acc[2]  = fmaf(av[t], b0.z, acc[2]);
            acc[3]  = fmaf(av[t], b0.w, acc[3]);
            acc[4]  = fmaf(av[t], b1.x, acc[4]);
            acc[5]  = fmaf(av[t], b1.y, acc[5]);
            acc[6]  = fmaf(av[t], b1.z, acc[6]);
            acc[7]  = fmaf(av[t], b1.w, acc[7]);
            acc[8]  = fmaf(av[t], b2.x, acc[8]);
            acc[9]  = fmaf(av[t], b2.y, acc[9]);
            acc[10] = fmaf(av[t], b2.z, acc[10]);
            acc[11] = fmaf(av[t], b2.w, acc[11]);
            acc[12] = fmaf(av[t], b3.x, acc[12]);
            acc[13] = fmaf(av[t], b3.y, acc[13]);
            acc[14] = fmaf(av[t], b3.z, acc[14]);
            acc[15] = fmaf(av[t], b3.w, acc[15]);
        }
    }
#pragma unroll
    for (int jj = 0; jj < 16; jj++) {
        int j = j0 + jj;
        float v = acc[jj];
        if (mode == 1) v += Dg[i * 64 + j];
        if (mode == 2) v = ((i == j) ? 1.f : 0.f) - v;
        Cg[i * 64 + j] = v;
        if (Cb) Cb[i * 64 + j] = f2bf(v);
    }
    __syncthreads();
}

__global__ __launch_bounds__(256) void kmc(
    const float* __restrict__ Ain, const float* __restrict__ Qin,
    const float* __restrict__ Hin, const float* __restrict__ Rin,
    float* __restrict__ AQg, float* __restrict__ Sg, float* __restrict__ Kg,
    float* __restrict__ Gg, float* __restrict__ T1, float* __restrict__ T2,
    float* __restrict__ Mw, float* __restrict__ M16w,
    unsigned short* __restrict__ Gb, unsigned short* __restrict__ Kb) {
    __shared__ __align__(16) char smem[50432];
    float* aug = (float*)smem;             // 64*129 = 33024 B
    float* Lx  = (float*)(smem + 33024);   // 64*68*4 = 17408 B
    float* prow2 = Lx;                     // [4][32] during GJ
    float* mcol  = Lx + 128;               // [64]
    int tid = threadIdx.x;

    mmc(Ain, Qin, AQg, Lx, 0, nullptr, nullptr, tid);   // AQ
    mmc(Hin, AQg, Sg, Lx, 1, Rin, nullptr, tid);        // S = Hm@AQ + R

    // aug = [S^T | AQ^T]  (coalesced global reads)
    for (int idx = tid; idx < 8192; idx += 256) {
        int i = idx & 63, j = idx >> 6;
        float v = (j < 64) ? Sg[j * 64 + i] : AQg[(j - 64) * 64 + i];
        aug[i * 129 + j] = v;
    }
    __syncthreads();

    // register-resident no-pivot Gauss-Jordan: solve S^T X = AQ^T -> X = K^T
    int i = tid & 63, jb = tid >> 6;
    float r[32];
#pragma unroll
    for (int u = 0; u < 32; u++) r[u] = aug[i * 129 + jb + 4 * u];
    __syncthreads();

    for (int k = 0; k < 64; k++) {
        if (i == k) {
#pragma unroll
            for (int q = 0; q < 8; q++) {
                float4 v4 = {r[4 * q], r[4 * q + 1], r[4 * q + 2], r[4 * q + 3]};
                *reinterpret_cast<float4*>(&prow2[jb * 32 + 4 * q]) = v4;
            }
        }
        if (jb == (k & 3)) {
            int usel = k >> 2;
            float v = r[0];
#pragma unroll
            for (int u = 1; u < 32; u++) v = (u == usel) ? r[u] : v;
            mcol[i] = v;
        }
        __syncthreads();
        float pv = prow2[(k & 3) * 32 + (k >> 2)];
        float rp = 1.0f / pv;
        float m = (i == k) ? (1.0f - rp) : mcol[i] * rp;
#pragma unroll
        for (int q = 0; q < 8; q++) {
            float4 p4 = *reinterpret_cast<const float4*>(&prow2[jb * 32 + 4 * q]);
            r[4 * q + 0] = fmaf(-m, p4.x, r[4 * q + 0]);
            r[4 * q + 1] = fmaf(-m, p4.y, r[4 * q + 1]);
            r[4 * q + 2] = fmaf(-m, p4.z, r[4 * q + 2]);
            r[4 * q + 3] = fmaf(-m, p4.w, r[4 * q + 3]);
        }
        __syncthreads();
    }

    // r[u], u>=16: K^T[i][jc], jc = jb + 4*(u-16)  ->  Ktmp = K row-major (in aug)
    float* Ktmp = aug;
#pragma unroll
    for (int u = 16; u < 32; u++) {
        int jc = jb + 4 * (u - 16);
        Ktmp[jc * 64 + i] = r[u];
    }
    __syncthreads();
    for (int idx = tid; idx < 4096; idx += 256) {
        float v = Ktmp[idx];
        Kg[idx] = v;
        Kb[idx] = f2bf(v);
    }
    __syncthreads();

    mmc(Kg, Hin, Gg, Lx, 2, nullptr, Gb, tid);      // G = I - K@Hm (+ bf16)
    mmc(Gg, Ain, Mw, Lx, 0, nullptr, nullptr, tid); // M = G@A
    mmc(Mw, Mw, T1, Lx, 0, nullptr, nullptr, tid);  // M^2
    mmc(T1, T1, T2, Lx, 0, nullptr, nullptr, tid);  // M^4
    mmc(T2, T2, T1, Lx, 0, nullptr, nullptr, tid);  // M^8
    mmc(T1, T1, M16w, Lx, 0, nullptr, nullptr, tid);// M^16
}

// ---------------------------------------------------------------------------
// kenc1 : encoder only, 64 rows/block, grid 2048.
//         GEMM1 -> relu -> GEMM2 -> reparam -> zmean/zlogv out, z bf16 -> zstg
// ---------------------------------------------------------------------------
__global__ __launch_bounds__(256) void kenc1(
    const float* __restrict__ x, const float* __restrict__ eps,
    const float* __restrict__ b1, const float* __restrict__ b2,
    const unsigned short* __restrict__ w1t, const unsigned short* __restrict__ w2t,
    unsigned short* __restrict__ zstg, float* __restrict__ zmean,
    float* __restrict__ zlogv) {
    __shared__ unsigned short Xs[64][72];
    __shared__ unsigned short Hs[64][264];
    __shared__ unsigned short Zs[64][72];
    int row0 = blockIdx.x * 64;
    int tid = threadIdx.x;
    int lane = tid & 63, w = tid >> 6;
    int ml = lane & 15, kg = lane >> 4;

    {   // stage X tile -> bf16 LDS
        int r = tid >> 2, c0 = (tid & 3) * 16;
        const float4* xp = reinterpret_cast<const float4*>(&x[(size_t)(row0 + r) * 64 + c0]);
        float4 v0 = xp[0], v1 = xp[1], v2 = xp[2], v3 = xp[3];
        short8 s0, s1;
        s0[0] = (short)f2bf(v0.x); s0[1] = (short)f2bf(v0.y);
        s0[2] = (short)f2bf(v0.z); s0[3] = (short)f2bf(v0.w);
        s0[4] = (short)f2bf(v1.x); s0[5] = (short)f2bf(v1.y);
        s0[6] = (short)f2bf(v1.z); s0[7] = (short)f2bf(v1.w);
        s1[0] = (short)f2bf(v2.x); s1[1] = (short)f2bf(v2.y);
        s1[2] = (short)f2bf(v2.z); s1[3] = (short)f2bf(v2.w);
        s1[4] = (short)f2bf(v3.x); s1[5] = (short)f2bf(v3.y);
        s1[6] = (short)f2bf(v3.z); s1[7] = (short)f2bf(v3.w);
        *reinterpret_cast<short8*>(&Xs[r][c0]) = s0;
        *reinterpret_cast<short8*>(&Xs[r][c0 + 8]) = s1;
    }
    __syncthreads();

    short8 afr[4][2];
#pragma unroll
    for (int mt = 0; mt < 4; mt++)
#pragma unroll
        for (int kb = 0; kb < 2; kb++)
            afr[mt][kb] = *reinterpret_cast<const short8*>(&Xs[mt * 16 + ml][kb * 32 + kg * 8]);

    // GEMM1: wave w -> n-tiles 4w..4w+3 of H[64,256]
#pragma unroll
    for (int q = 0; q < 4; q++) {
        int nt = w * 4 + q;
        f32x4 acc[4];
#pragma unroll
        for (int mt = 0; mt < 4; mt++) acc[mt] = (f32x4){0.f, 0.f, 0.f, 0.f};
#pragma unroll
        for (int kb = 0; kb < 2; kb++) {
            short8 bfr = *reinterpret_cast<const short8*>(&w1t[(nt * 16 + ml) * 64 + kb * 32 + kg * 8]);
#pragma unroll
            for (int mt = 0; mt < 4; mt++)
                acc[mt] = __builtin_amdgcn_mfma_f32_16x16x32_bf16(afr[mt][kb], bfr, acc[mt], 0, 0, 0);
        }
        float bias = b1[nt * 16 + ml];
#pragma unroll
        for (int mt = 0; mt < 4; mt++)
#pragma unroll
            for (int i = 0; i < 4; i++) {
                float v = acc[mt][i] + bias;
                v = v > 0.f ? v : 0.f;
                Hs[mt * 16 + kg * 4 + i][nt * 16 + ml] = f2bf(v);
            }
    }
    __syncthreads();

    // GEMM2: wave w -> n-tiles {w, w+4} of ML[64,128]
    f32x4 acc2[2][4];
#pragma unroll
    for (int p = 0; p < 2; p++)
#pragma unroll
        for (int mt = 0; mt < 4; mt++) acc2[p][mt] = (f32x4){0.f, 0.f, 0.f, 0.f};
#pragma unroll
    for (int kb = 0; kb < 8; kb++) {
        short8 a2[4];
#pragma unroll
        for (int mt = 0; mt < 4; mt++)
            a2[mt] = *reinterpret_cast<const short8*>(&Hs[mt * 16 + ml][kb * 32 + kg * 8]);
#pragma unroll
        for (int p = 0; p < 2; p++) {
            int nt = w + 4 * p;
            short8 bfr = *reinterpret_cast<const short8*>(&w2t[(nt * 16 + ml) * 256 + kb * 32 + kg * 8]);
#pragma unroll
            for (int mt = 0; mt < 4; mt++)
                acc2[p][mt] = __builtin_amdgcn_mfma_f32_16x16x32_bf16(a2[mt], bfr, acc2[p][mt], 0, 0, 0);
        }
    }
    int colz = w * 16 + ml;
    float bm = b2[colz], bl = b2[64 + colz];
#pragma unroll
    for (int mt = 0; mt < 4; mt++)
#pragma unroll
        for (int i = 0; i < 4; i++) {
            int r = mt * 16 + kg * 4 + i;
            size_t grow = (size_t)(row0 + r);
            float zm = acc2[0][mt][i] + bm;
            float zl = acc2[1][mt][i] + bl;
            zmean[grow * 64 + colz] = zm;
            zlogv[grow * 64 + colz] = zl;
            float zz = zm + eps[grow * 64 + colz] * expf(0.5f * zl);
            Zs[r][colz] = f2bf(zz);
        }
    __syncthreads();

    {   // coalesced zstg store
        int r = tid >> 2, c0 = (tid & 3) * 16;
        short8 s0 = *reinterpret_cast<const short8*>(&Zs[r][c0]);
        short8 s1 = *reinterpret_cast<const short8*>(&Zs[r][c0 + 8]);
        *reinterpret_cast<short8*>(&zstg[(size_t)(row0 + r) * 64 + c0]) = s0;
        *reinterpret_cast<short8*>(&zstg[(size_t)(row0 + r) * 64 + c0 + 8]) = s1;
    }
}

// ---------------------------------------------------------------------------
// kenc2 : c = z@G^T + x@K^T -> cbuf bf16 + phase-A chunk scans -> Pbuf
// ---------------------------------------------------------------------------
__global__ __launch_bounds__(256) void kenc2(
    const float* __restrict__ x, const unsigned short* __restrict__ zstg,
    const unsigned short* __restrict__ Gb, const unsigned short* __restrict__ Kb,
    const float* __restrict__ Mw, unsigned short* __restrict__ cbuf,
    float* __restrict__ Pbuf) {
    __shared__ unsigned short Xs[64][72];
    __shared__ unsigned short Cs[64][72];
    int row0 = blockIdx.x * 64;
    int tid = threadIdx.x;
    int lane = tid & 63, w = tid >> 6;
    int ml = lane & 15, kg = lane >> 4;

    {   // stage X tile -> bf16 LDS
        int r = tid >> 2, c0 = (tid & 3) * 16;
        const float4* xp = reinterpret_cast<const float4*>(&x[(size_t)(row0 + r) * 64 + c0]);
        float4 v0 = xp[0], v1 = xp[1], v2 = xp[2], v3 = xp[3];
        short8 s0, s1;
        s0[0] = (short)f2bf(v0.x); s0[1] = (short)f2bf(v0.y);
        s0[2] = (short)f2bf(v0.z); s0[3] = (short)f2bf(v0.w);
        s0[4] = (short)f2bf(v1.x); s0[5] = (short)f2bf(v1.y);
        s0[6] = (short)f2bf(v1.z); s0[7] = (short)f2bf(v1.w);
        s1[0] = (short)f2bf(v2.x); s1[1] = (short)f2bf(v2.y);
        s1[2] = (short)f2bf(v2.z); s1[3] = (short)f2bf(v2.w);
        s1[4] = (short)f2bf(v3.x); s1[5] = (short)f2bf(v3.y);
        s1[6] = (short)f2bf(v3.z); s1[7] = (short)f2bf(v3.w);
        *reinterpret_cast<short8*>(&Xs[r][c0]) = s0;
        *reinterpret_cast<short8*>(&Xs[r][c0 + 8]) = s1;
    }
    __syncthreads();

    int colz = w * 16 + ml;
    f32x4 acc3[4];
#pragma unroll
    for (int mt = 0; mt < 4; mt++) acc3[mt] = (f32x4){0.f, 0.f, 0.f, 0.f};
#pragma unroll
    for (int kb = 0; kb < 2; kb++) {
        short8 bg = *reinterpret_cast<const short8*>(&Gb[(w * 16 + ml) * 64 + kb * 32 + kg * 8]);
        short8 bk = *reinterpret_cast<const short8*>(&Kb[(w * 16 + ml) * 64 + kb * 32 + kg * 8]);
#pragma unroll
        for (int mt = 0; mt < 4; mt++) {
            short8 az = *reinterpret_cast<const short8*>(
                &zstg[(size_t)(row0 + mt * 16 + ml) * 64 + kb * 32 + kg * 8]);
            acc3[mt] = __builtin_amdgcn_mfma_f32_16x16x32_bf16(az, bg, acc3[mt], 0, 0, 0);
            short8 ax = *reinterpret_cast<const short8*>(&Xs[mt * 16 + ml][kb * 32 + kg * 8]);
            acc3[mt] = __builtin_amdgcn_mfma_f32_16x16x32_bf16(ax, bk, acc3[mt], 0, 0, 0);
        }
    }
#pragma unroll
    for (int mt = 0; mt < 4; mt++)
#pragma unroll
        for (int i = 0; i < 4; i++)
            Cs[mt * 16 + kg * 4 + i][colz] = f2bf(acc3[mt][i]);
    __syncthreads();

    {   // coalesced cbuf store
        int r = tid >> 2, c0 = (tid & 3) * 16;
        short8 s0 = *reinterpret_cast<const short8*>(&Cs[r][c0]);
        short8 s1 = *reinterpret_cast<const short8*>(&Cs[r][c0 + 8]);
        *reinterpret_cast<short8*>(&cbuf[(size_t)(row0 + r) * 64 + c0]) = s0;
        *reinterpret_cast<short8*>(&cbuf[(size_t)(row0 + r) * 64 + c0 + 8]) = s1;
    }

    {   // phase-A local scan: wave w scans chunk rows [16w,16w+16), zero init
        int j = lane;
        float m[64];
        load_mrow(Mw, j, m);
        unsigned short cv[16];
#pragma unroll
        for (int t = 0; t < 16; t++) cv[t] = Cs[w * 16 + t][j];
        float z = bf2f(cv[0]);
#pragma unroll
        for (int t = 1; t < 16; t++) z = matvec_rl(m, z, bf2f(cv[t]));
        int b = row0 >> 9;
        int chunk = ((row0 & 511) >> 4) + w;        // 0..31
        if (chunk != 31)
            Pbuf[((size_t)b * 32 + chunk + 1) * 64 + j] = z;
    }
}

// ---------------------------------------------------------------------------
// kchain : per batch, P[0]=0 ; P[c] = f[c-1] + M16 P[c-1]  (in-place, prefetch)
// ---------------------------------------------------------------------------
__global__ __launch_bounds__(64) void kchain(const float* __restrict__ M16w,
                                             float* __restrict__ Pbuf) {
    int b = blockIdx.x, j = threadIdx.x;
    float m[64];
    load_mrow(M16w, j, m);
    float* P = Pbuf + (size_t)b * 32 * 64;
    float fnext = P[64 + j];
    P[j] = 0.f;                                     // P[0]
    float z = 0.f;
    for (int c = 1; c < 32; c++) {
        float f = fnext;
        if (c < 31) fnext = P[(c + 1) * 64 + j];
        z = matvec_rl(m, z, f);
        P[c * 64 + j] = z;
    }
}

// ---------------------------------------------------------------------------
// kdec : phase-C chunk scans -> decoder GEMMs -> x_recon
// ---------------------------------------------------------------------------
__global__ __launch_bounds__(256) void kdec(float* __restrict__ xr,
                                            const float* __restrict__ db1,
                                            const float* __restrict__ db2,
                                            const unsigned short* __restrict__ d1t,
                                            const unsigned short* __restrict__ d2t,
                                            const float* __restrict__ Mw,
                                            const float* __restrict__ Pbuf,
                                            const unsigned short* __restrict__ cbuf) {
    __shared__ unsigned short Zs[64][72];
    __shared__ unsigned short Hs[64][264];
    int row0 = blockIdx.x * 64;
    int tid = threadIdx.x;
    int lane = tid & 63, w = tid >> 6;
    int ml = lane & 15, kg = lane >> 4;

    {   // phase-C scan
        int j = lane;
        int b = row0 >> 9;
        int chunk = ((row0 & 511) >> 4) + w;
        float m[64];
        load_mrow(Mw, j, m);
        float z = Pbuf[((size_t)b * 32 + chunk) * 64 + j];
        const unsigned short* cb = cbuf + ((size_t)row0 + w * 16) * 64;
        unsigned short cv[16];
#pragma unroll
        for (int t = 0; t < 16; t++) cv[t] = cb[t * 64 + j];
#pragma unroll
        for (int t = 0; t < 16; t++) {
            z = matvec_rl(m, z, bf2f(cv[t]));
            Zs[w * 16 + t][j] = f2bf(z);
        }
    }
    __syncthreads();

    short8 afr[4][2];
#pragma unroll
    for (int mt = 0; mt < 4; mt++)
#pragma unroll
        for (int kb = 0; kb < 2; kb++)
            afr[mt][kb] = *reinterpret_cast<const short8*>(&Zs[mt * 16 + ml][kb * 32 + kg * 8]);

#pragma unroll
    for (int q = 0; q < 4; q++) {
        int nt = w * 4 + q;
        f32x4 acc[4];
#pragma unroll
        for (int mt = 0; mt < 4; mt++) acc[mt] = (f32x4){0.f, 0.f, 0.f, 0.f};
#pragma unroll
        for (int kb = 0; kb < 2; kb++) {
            short8 bfr = *reinterpret_cast<const short8*>(&d1t[(nt * 16 + ml) * 64 + kb * 32 + kg * 8]);
#pragma unroll
            for (int mt = 0; mt < 4; mt++)
                acc[mt] = __builtin_amdgcn_mfma_f32_16x16x32_bf16(afr[mt][kb], bfr, acc[mt], 0, 0, 0);
        }
        float bias = db1[nt * 16 + ml];
#pragma unroll
        for (int mt = 0; mt < 4; mt++)
#pragma unroll
            for (int i = 0; i < 4; i++) {
                float v = acc[mt][i] + bias;
                v = v > 0.f ? v : 0.f;
                Hs[mt * 16 + kg * 4 + i][nt * 16 + ml] = f2bf(v);
            }
    }
    __syncthreads();

    f32x4 acc2[4];
#pragma unroll
    for (int mt = 0; mt < 4; mt++) acc2[mt] = (f32x4){0.f, 0.f, 0.f, 0.f};
#pragma unroll
    for (int kb = 0; kb < 8; kb++) {
        short8 bfr = *reinterpret_cast<const short8*>(&d2t[(w * 16 + ml) * 256 + kb * 32 + kg * 8]);
#pragma unroll
        for (int mt = 0; mt < 4; mt++) {
            short8 a2 = *reinterpret_cast<const short8*>(&Hs[mt * 16 + ml][kb * 32 + kg * 8]);
            acc2[mt] = __builtin_amdgcn_mfma_f32_16x16x32_bf16(a2, bfr, acc2[mt], 0, 0, 0);
        }
    }
    float bias2 = db2[w * 16 + ml];
#pragma unroll
    for (int mt = 0; mt < 4; mt++)
#pragma unroll
        for (int i = 0; i < 4; i++) {
            int r = mt * 16 + kg * 4 + i;
            float v = acc2[mt][i] + bias2;
            float s = 1.f / (1.f + expf(-v));
            xr[(size_t)(row0 + r) * 64 + w * 16 + ml] = s;
        }
}

// ---------------------------------------------------------------------------
extern "C" void kernel_launch(void* const* d_in, const int* in_sizes, int n_in,
                              void* d_out, int out_size, void* d_ws, size_t ws_size,
                              hipStream_t stream) {
    (void)in_sizes; (void)n_in; (void)out_size; (void)ws_size;
    const float* x      = (const float*)d_in[0];
    const float* eps    = (const float*)d_in[1];
    const float* enc_w1 = (const float*)d_in[2];
    const float* enc_b1 = (const float*)d_in[3];
    const float* enc_w2 = (const float*)d_in[4];
    const float* enc_b2 = (const float*)d_in[5];
    const float* dec_w1 = (const float*)d_in[6];
    const float* dec_b1 = (const float*)d_in[7];
    const float* dec_w2 = (const float*)d_in[8];
    const float* dec_b2 = (const float*)d_in[9];
    const float* Ain    = (const float*)d_in[10];
    const float* Qin    = (const float*)d_in[11];
    const float* Hin    = (const float*)d_in[12];
    const float* Rin    = (const float*)d_in[13];

    float* out   = (float*)d_out;
    float* xrec  = out;                              // x_recon; zstg staging
    float* zmean = out + OUTSEG;
    float* zlogv = out + 2 * OUTSEG;
    unsigned short* zstg = (unsigned short*)xrec;    // 16.8 MB of 33.5 MB region

    char* ws = (char*)d_ws;
    float*          Mw   = (float*)(ws);                    // 16 KB
    float*          M16w = (float*)(ws + 16384);            // 16 KB
    float*          AQg  = (float*)(ws + 32768);            // 16 KB
    float*          Sg   = (float*)(ws + 49152);            // 16 KB
    float*          Kg   = (float*)(ws + 65536);            // 16 KB
    float*          Gg   = (float*)(ws + 81920);            // 16 KB
    float*          T1   = (float*)(ws + 98304);            // 16 KB
    float*          T2   = (float*)(ws + 114688);           // 16 KB
    unsigned short* Gb   = (unsigned short*)(ws + 131072);  // 8 KB
    unsigned short* Kb   = (unsigned short*)(ws + 139264);  // 8 KB
    unsigned short* w1t  = (unsigned short*)(ws + 147456);  // 32 KB
    unsigned short* w2t  = (unsigned short*)(ws + 180224);  // 64 KB
    unsigned short* d1t  = (unsigned short*)(ws + 245760);  // 32 KB
    unsigned short* d2t  = (unsigned short*)(ws + 278528);  // 32 KB
    float*          Pbuf = (float*)(ws + 311296);           // 2 MB
    unsigned short* cbuf = (unsigned short*)(ws + 2408448); // 16.8 MB (end ~18.3MB)

    hipLaunchKernelGGL(ktr, dim3(20), dim3(256), 0, stream,
                       enc_w1, enc_w2, dec_w1, dec_w2, w1t, w2t, d1t, d2t);
    hipLaunchKernelGGL(kenc1, dim3(2048), dim3(256), 0, stream,
                       x, eps, enc_b1, enc_b2, w1t, w2t, zstg, zmean, zlogv);
    hipLaunchKernelGGL(kmc, dim3(1), dim3(256), 0, stream,
                       Ain, Qin, Hin, Rin, AQg, Sg, Kg, Gg, T1, T2, Mw, M16w,
                       Gb, Kb);
    hipLaunchKernelGGL(kenc2, dim3(2048), dim3(256), 0, stream,
                       x, zstg, Gb, Kb, Mw, cbuf, Pbuf);
    hipLaunchKernelGGL(kchain, dim3(256), dim3(64), 0, stream, M16w, Pbuf);
    hipLaunchKernelGGL(kdec, dim3(2048), dim3(256), 0, stream,
                       xrec, dec_b1, dec_b2, d1t, d2t, Mw, Pbuf, cbuf);
}

// Round 6
// 620.353 us; speedup vs baseline: 1.6030x; 1.6030x over previous
//
#include <hip/hip_runtime.h>
#include <hip/hip_bf16.h>

// ---------------------------------------------------------------------------
// KalmanVAE: B=256, S=512, D=64, L=64, HID=256
// out = [x_recon | z_mean | z_logvar], each 131072*64 fp32
//
// z_up_t = M z_{t-1} + c_t,  M = (I-K Hm) A,  c_t = G z_t + K x_t, G = I-K Hm
// Kernels:
//   ktr   : 20 blocks, bf16 transposed weight copies.
//   kenc1 : encoder GEMMs + reparam -> zstg bf16 (out region 0), zmean/zlogv.
//   kmc   : 1 block. Rewritten chain: LDS broadcast-b128 matmuls (4 waves) +
//           single-wave register-resident readlane Gauss-Jordan (no pivot,
//           fully unrolled -> all register indices static, no scratch).
//   kenc2 : c = z@G^T + x@K^T -> cbuf bf16 + phase-A chunk scans -> Pbuf.
//   kchain: per-batch chunk prefix with M^16 (prefetched).
//   kdec  : phase-C chunk scans -> decoder GEMMs -> x_recon.
// ---------------------------------------------------------------------------

typedef short short8 __attribute__((ext_vector_type(8)));
typedef float f32x4 __attribute__((ext_vector_type(4)));

#define OUTSEG 8388608   // 131072*64

__device__ __forceinline__ unsigned short f2bf(float f) {
    unsigned int u = __builtin_bit_cast(unsigned int, f);
    u += 0x7fffu + ((u >> 16) & 1u);   // RNE
    return (unsigned short)(u >> 16);
}
__device__ __forceinline__ float bf2f(unsigned short h) {
    unsigned int u = ((unsigned int)h) << 16;
    return __builtin_bit_cast(float, u);
}
__device__ __forceinline__ float rlf(float v, int l) {
    return __builtin_bit_cast(float, __builtin_amdgcn_readlane(__builtin_bit_cast(int, v), l));
}
// z_new[j] = c[j] + sum_k m[k] * z[k]   (m = row j of M, one wave, no barriers)
__device__ __forceinline__ float matvec_rl(const float* m, float z, float c) {
    float a0 = c, a1 = 0.f, a2 = 0.f, a3 = 0.f;
#pragma unroll
    for (int k = 0; k < 64; k += 4) {
        a0 = fmaf(m[k + 0], rlf(z, k + 0), a0);
        a1 = fmaf(m[k + 1], rlf(z, k + 1), a1);
        a2 = fmaf(m[k + 2], rlf(z, k + 2), a2);
        a3 = fmaf(m[k + 3], rlf(z, k + 3), a3);
    }
    return (a0 + a1) + (a2 + a3);
}
__device__ __forceinline__ void load_mrow(const float* Mp, int j, float* m) {
#pragma unroll
    for (int q = 0; q < 16; q++) {
        float4 v = *reinterpret_cast<const float4*>(&Mp[j * 64 + q * 4]);
        m[q * 4 + 0] = v.x; m[q * 4 + 1] = v.y;
        m[q * 4 + 2] = v.z; m[q * 4 + 3] = v.w;
    }
}

// ---------------------------------------------------------------------------
// ktr : weight transposes (bf16), 20 blocks x 256 threads
// ---------------------------------------------------------------------------
__device__ void tr_tile(const float* src, int sld, unsigned short* dst, int dld,
                        int r0, int c0, int tid, float* LT) {
    int rr = tid >> 2, q = tid & 3;
#pragma unroll
    for (int u = 0; u < 4; u++) {
        float4 v = *reinterpret_cast<const float4*>(
            &src[(size_t)(r0 + rr) * sld + c0 + q * 16 + u * 4]);
        LT[rr * 65 + q * 16 + u * 4 + 0] = v.x;
        LT[rr * 65 + q * 16 + u * 4 + 1] = v.y;
        LT[rr * 65 + q * 16 + u * 4 + 2] = v.z;
        LT[rr * 65 + q * 16 + u * 4 + 3] = v.w;
    }
    __syncthreads();
    short8 s0, s1;
#pragma unroll
    for (int u = 0; u < 8; u++) s0[u] = (short)f2bf(LT[(q * 16 + u) * 65 + rr]);
#pragma unroll
    for (int u = 0; u < 8; u++) s1[u] = (short)f2bf(LT[(q * 16 + 8 + u) * 65 + rr]);
    *reinterpret_cast<short8*>(&dst[(size_t)(c0 + rr) * dld + r0 + q * 16]) = s0;
    *reinterpret_cast<short8*>(&dst[(size_t)(c0 + rr) * dld + r0 + q * 16 + 8]) = s1;
}

__global__ __launch_bounds__(256) void ktr(
    const float* __restrict__ ew1, const float* __restrict__ ew2,
    const float* __restrict__ dw1, const float* __restrict__ dw2,
    unsigned short* __restrict__ w1t, unsigned short* __restrict__ w2t,
    unsigned short* __restrict__ d1t, unsigned short* __restrict__ d2t) {
    __shared__ float La[64 * 65];
    int tid = threadIdx.x;
    int t = blockIdx.x;
    const float* src; unsigned short* dst; int sld, dld, r0, c0;
    if (t < 4)       { src = ew1; dst = w1t; sld = 256; dld = 64;  r0 = 0;             c0 = t * 64; }
    else if (t < 12) { int i = t - 4;  src = ew2; dst = w2t; sld = 128; dld = 256; r0 = (i >> 1) * 64; c0 = (i & 1) * 64; }
    else if (t < 16) { int i = t - 12; src = dw1; dst = d1t; sld = 256; dld = 64;  r0 = 0;             c0 = i * 64; }
    else             { int i = t - 16; src = dw2; dst = d2t; sld = 64;  dld = 256; r0 = i * 64;        c0 = 0; }
    tr_tile(src, sld, dst, dld, r0, c0, tid, La);
}

// ---------------------------------------------------------------------------
// kmc : matrix chain, 1 block x 256 threads. LDS pitch 68 floats (16B-align).
// ---------------------------------------------------------------------------
__device__ __forceinline__ void stage4(const float* __restrict__ g, float* L, int tid) {
#pragma unroll
    for (int n = 0; n < 16; n++) {
        int idx = tid + n * 256;
        L[(idx >> 6) * 68 + (idx & 63)] = g[idx];
    }
}

// C = A@B (mode 0) ; C = A@B + Dg (mode 1, Dg global pitch 64) ; C = I - A@B (2)
// A-row in regs (b128), B via wave-uniform broadcast b128. Barrier at end.
__device__ __forceinline__ void mml(const float* pa, const float* pb, float* pc,
                                    int mode, const float* __restrict__ gd,
                                    float* __restrict__ gout,
                                    unsigned short* __restrict__ bout, int tid) {
    int i = tid & 63, j0 = (tid >> 6) * 16;
    float a[64];
#pragma unroll
    for (int u = 0; u < 16; u++) {
        float4 v = *reinterpret_cast<const float4*>(&pa[i * 68 + u * 4]);
        a[u * 4 + 0] = v.x; a[u * 4 + 1] = v.y;
        a[u * 4 + 2] = v.z; a[u * 4 + 3] = v.w;
    }
    float acc[4][4];
#pragma unroll
    for (int q = 0; q < 4; q++)
#pragma unroll
        for (int e = 0; e < 4; e++) acc[q][e] = 0.f;
#pragma unroll 4
    for (int k = 0; k < 64; k++) {
        float ak = a[k];
#pragma unroll
        for (int q = 0; q < 4; q++) {
            float4 b = *reinterpret_cast<const float4*>(&pb[k * 68 + j0 + q * 4]);
            acc[q][0] = fmaf(ak, b.x, acc[q][0]);
            acc[q][1] = fmaf(ak, b.y, acc[q][1]);
            acc[q][2] = fmaf(ak, b.z, acc[q][2]);
            acc[q][3] = fmaf(ak, b.w, acc[q][3]);
        }
    }
#pragma unroll
    for (int q = 0; q < 4; q++) {
        int j = j0 + q * 4;
        if (mode == 1) {
            float4 d = *reinterpret_cast<const float4*>(&gd[i * 64 + j]);
            acc[q][0] += d.x; acc[q][1] += d.y; acc[q][2] += d.z; acc[q][3] += d.w;
        } else if (mode == 2) {
#pragma unroll
            for (int e = 0; e < 4; e++)
                acc[q][e] = ((i == j + e) ? 1.f : 0.f) - acc[q][e];
        }
        float4 v = {acc[q][0], acc[q][1], acc[q][2], acc[q][3]};
        *reinterpret_cast<float4*>(&pc[i * 68 + j]) = v;
        if (gout) *reinterpret_cast<float4*>(&gout[i * 64 + j]) = v;
        if (bout) {
            bout[i * 64 + j + 0] = f2bf(v.x);
            bout[i * 64 + j + 1] = f2bf(v.y);
            bout[i * 64 + j + 2] = f2bf(v.z);
            bout[i * 64 + j + 3] = f2bf(v.w);
        }
    }
    __syncthreads();
}

__global__ __launch_bounds__(256) void kmc(
    const float* __restrict__ Ain, const float* __restrict__ Qin,
    const float* __restrict__ Hin, const float* __restrict__ Rin,
    float* __restrict__ Mw, float* __restrict__ M16w,
    unsigned short* __restrict__ Gb, unsigned short* __restrict__ Kb) {
    __shared__ __align__(16) float LB[4 * 64 * 68];   // 69632 B
    float* B0 = LB;                 // A      -> M2 -> M16
    float* B1 = LB + 4352;          // Q -> S -> G  -> M4
    float* B2 = LB + 8704;          // AQ -> K -> M -> M8
    float* B3 = LB + 13056;         // Hm
    int tid = threadIdx.x;

    stage4(Ain, B0, tid);
    stage4(Qin, B1, tid);
    stage4(Hin, B3, tid);
    __syncthreads();

    mml(B0, B1, B2, 0, nullptr, nullptr, nullptr, tid);   // B2 = AQ
    mml(B3, B2, B1, 1, Rin,     nullptr, nullptr, tid);   // B1 = S = Hm@AQ + R

    // ---- single-wave register GJ: solve S^T X = AQ^T  (X = K^T) ----
    // lane j holds column j of [S^T | AQ^T] = (row j of S | row j of AQ)
    if (tid < 64) {
        int j = tid;
        float r[64], q[64];
#pragma unroll
        for (int u = 0; u < 16; u++) {
            float4 v = *reinterpret_cast<const float4*>(&B1[j * 68 + u * 4]);
            r[u * 4 + 0] = v.x; r[u * 4 + 1] = v.y;
            r[u * 4 + 2] = v.z; r[u * 4 + 3] = v.w;
            float4 w = *reinterpret_cast<const float4*>(&B2[j * 68 + u * 4]);
            q[u * 4 + 0] = w.x; q[u * 4 + 1] = w.y;
            q[u * 4 + 2] = w.z; q[u * 4 + 3] = w.w;
        }
#pragma unroll
        for (int k = 0; k < 64; k++) {
            float pv = rlf(r[k], k);          // aug[k][k], uniform
            float rp = 1.0f / pv;
            float tL = r[k] * rp;             // scaled pivot-row elem, this column
            float tR = q[k] * rp;
#pragma unroll
            for (int i = 0; i < 64; i++) {
                if (i == k) continue;
                float mi = rlf(r[i], k);      // aug[i][k], uniform
                r[i] = fmaf(-mi, tL, r[i]);
                q[i] = fmaf(-mi, tR, q[i]);
            }
            r[k] = tL; q[k] = tR;
        }
        // lane j now holds K row j in q[] (K^T[:,j]). Write K -> B2 + Kb bf16.
#pragma unroll
        for (int u = 0; u < 16; u++) {
            float4 v = {q[u * 4], q[u * 4 + 1], q[u * 4 + 2], q[u * 4 + 3]};
            *reinterpret_cast<float4*>(&B2[j * 68 + u * 4]) = v;
        }
#pragma unroll
        for (int u = 0; u < 8; u++) {
            short8 s;
#pragma unroll
            for (int e = 0; e < 8; e++) s[e] = (short)f2bf(q[u * 8 + e]);
            *reinterpret_cast<short8*>(&Kb[j * 64 + u * 8]) = s;
        }
    }
    __syncthreads();

    mml(B2, B3, B1, 2, nullptr, nullptr, Gb, tid);        // B1 = G = I - K@Hm
    mml(B1, B0, B2, 0, nullptr, Mw, nullptr, tid);        // B2 = M = G@A
    mml(B2, B2, B0, 0, nullptr, nullptr, nullptr, tid);   // B0 = M^2
    mml(B0, B0, B1, 0, nullptr, nullptr, nullptr, tid);   // B1 = M^4
    mml(B1, B1, B2, 0, nullptr, nullptr, nullptr, tid);   // B2 = M^8
    mml(B2, B2, B0, 0, nullptr, M16w, nullptr, tid);      // B0 = M^16 (+global)
}

// ---------------------------------------------------------------------------
// kenc1 : encoder only, 64 rows/block, grid 2048.
//         GEMM1 -> relu -> GEMM2 -> reparam -> zmean/zlogv out, z bf16 -> zstg
// ---------------------------------------------------------------------------
__global__ __launch_bounds__(256) void kenc1(
    const float* __restrict__ x, const float* __restrict__ eps,
    const float* __restrict__ b1, const float* __restrict__ b2,
    const unsigned short* __restrict__ w1t, const unsigned short* __restrict__ w2t,
    unsigned short* __restrict__ zstg, float* __restrict__ zmean,
    float* __restrict__ zlogv) {
    __shared__ unsigned short Xs[64][72];
    __shared__ unsigned short Hs[64][264];
    __shared__ unsigned short Zs[64][72];
    int row0 = blockIdx.x * 64;
    int tid = threadIdx.x;
    int lane = tid & 63, w = tid >> 6;
    int ml = lane & 15, kg = lane >> 4;

    {   // stage X tile -> bf16 LDS
        int r = tid >> 2, c0 = (tid & 3) * 16;
        const float4* xp = reinterpret_cast<const float4*>(&x[(size_t)(row0 + r) * 64 + c0]);
        float4 v0 = xp[0], v1 = xp[1], v2 = xp[2], v3 = xp[3];
        short8 s0, s1;
        s0[0] = (short)f2bf(v0.x); s0[1] = (short)f2bf(v0.y);
        s0[2] = (short)f2bf(v0.z); s0[3] = (short)f2bf(v0.w);
        s0[4] = (short)f2bf(v1.x); s0[5] = (short)f2bf(v1.y);
        s0[6] = (short)f2bf(v1.z); s0[7] = (short)f2bf(v1.w);
        s1[0] = (short)f2bf(v2.x); s1[1] = (short)f2bf(v2.y);
        s1[2] = (short)f2bf(v2.z); s1[3] = (short)f2bf(v2.w);
        s1[4] = (short)f2bf(v3.x); s1[5] = (short)f2bf(v3.y);
        s1[6] = (short)f2bf(v3.z); s1[7] = (short)f2bf(v3.w);
        *reinterpret_cast<short8*>(&Xs[r][c0]) = s0;
        *reinterpret_cast<short8*>(&Xs[r][c0 + 8]) = s1;
    }
    __syncthreads();

    short8 afr[4][2];
#pragma unroll
    for (int mt = 0; mt < 4; mt++)
#pragma unroll
        for (int kb = 0; kb < 2; kb++)
            afr[mt][kb] = *reinterpret_cast<const short8*>(&Xs[mt * 16 + ml][kb * 32 + kg * 8]);

    // GEMM1: wave w -> n-tiles 4w..4w+3 of H[64,256]
#pragma unroll
    for (int q = 0; q < 4; q++) {
        int nt = w * 4 + q;
        f32x4 acc[4];
#pragma unroll
        for (int mt = 0; mt < 4; mt++) acc[mt] = (f32x4){0.f, 0.f, 0.f, 0.f};
#pragma unroll
        for (int kb = 0; kb < 2; kb++) {
            short8 bfr = *reinterpret_cast<const short8*>(&w1t[(nt * 16 + ml) * 64 + kb * 32 + kg * 8]);
#pragma unroll
            for (int mt = 0; mt < 4; mt++)
                acc[mt] = __builtin_amdgcn_mfma_f32_16x16x32_bf16(afr[mt][kb], bfr, acc[mt], 0, 0, 0);
        }
        float bias = b1[nt * 16 + ml];
#pragma unroll
        for (int mt = 0; mt < 4; mt++)
#pragma unroll
            for (int i = 0; i < 4; i++) {
                float v = acc[mt][i] + bias;
                v = v > 0.f ? v : 0.f;
                Hs[mt * 16 + kg * 4 + i][nt * 16 + ml] = f2bf(v);
            }
    }
    __syncthreads();

    // GEMM2: wave w -> n-tiles {w, w+4} of ML[64,128]
    f32x4 acc2[2][4];
#pragma unroll
    for (int p = 0; p < 2; p++)
#pragma unroll
        for (int mt = 0; mt < 4; mt++) acc2[p][mt] = (f32x4){0.f, 0.f, 0.f, 0.f};
#pragma unroll
    for (int kb = 0; kb < 8; kb++) {
        short8 a2[4];
#pragma unroll
        for (int mt = 0; mt < 4; mt++)
            a2[mt] = *reinterpret_cast<const short8*>(&Hs[mt * 16 + ml][kb * 32 + kg * 8]);
#pragma unroll
        for (int p = 0; p < 2; p++) {
            int nt = w + 4 * p;
            short8 bfr = *reinterpret_cast<const short8*>(&w2t[(nt * 16 + ml) * 256 + kb * 32 + kg * 8]);
#pragma unroll
            for (int mt = 0; mt < 4; mt++)
                acc2[p][mt] = __builtin_amdgcn_mfma_f32_16x16x32_bf16(a2[mt], bfr, acc2[p][mt], 0, 0, 0);
        }
    }
    int colz = w * 16 + ml;
    float bm = b2[colz], bl = b2[64 + colz];
#pragma unroll
    for (int mt = 0; mt < 4; mt++)
#pragma unroll
        for (int i = 0; i < 4; i++) {
            int r = mt * 16 + kg * 4 + i;
            size_t grow = (size_t)(row0 + r);
            float zm = acc2[0][mt][i] + bm;
            float zl = acc2[1][mt][i] + bl;
            zmean[grow * 64 + colz] = zm;
            zlogv[grow * 64 + colz] = zl;
            float zz = zm + eps[grow * 64 + colz] * expf(0.5f * zl);
            Zs[r][colz] = f2bf(zz);
        }
    __syncthreads();

    {   // coalesced zstg store
        int r = tid >> 2, c0 = (tid & 3) * 16;
        short8 s0 = *reinterpret_cast<const short8*>(&Zs[r][c0]);
        short8 s1 = *reinterpret_cast<const short8*>(&Zs[r][c0 + 8]);
        *reinterpret_cast<short8*>(&zstg[(size_t)(row0 + r) * 64 + c0]) = s0;
        *reinterpret_cast<short8*>(&zstg[(size_t)(row0 + r) * 64 + c0 + 8]) = s1;
    }
}

// ---------------------------------------------------------------------------
// kenc2 : c = z@G^T + x@K^T -> cbuf bf16 + phase-A chunk scans -> Pbuf
// ---------------------------------------------------------------------------
__global__ __launch_bounds__(256) void kenc2(
    const float* __restrict__ x, const unsigned short* __restrict__ zstg,
    const unsigned short* __restrict__ Gb, const unsigned short* __restrict__ Kb,
    const float* __restrict__ Mw, unsigned short* __restrict__ cbuf,
    float* __restrict__ Pbuf) {
    __shared__ unsigned short Xs[64][72];
    __shared__ unsigned short Cs[64][72];
    int row0 = blockIdx.x * 64;
    int tid = threadIdx.x;
    int lane = tid & 63, w = tid >> 6;
    int ml = lane & 15, kg = lane >> 4;

    {   // stage X tile -> bf16 LDS
        int r = tid >> 2, c0 = (tid & 3) * 16;
        const float4* xp = reinterpret_cast<const float4*>(&x[(size_t)(row0 + r) * 64 + c0]);
        float4 v0 = xp[0], v1 = xp[1], v2 = xp[2], v3 = xp[3];
        short8 s0, s1;
        s0[0] = (short)f2bf(v0.x); s0[1] = (short)f2bf(v0.y);
        s0[2] = (short)f2bf(v0.z); s0[3] = (short)f2bf(v0.w);
        s0[4] = (short)f2bf(v1.x); s0[5] = (short)f2bf(v1.y);
        s0[6] = (short)f2bf(v1.z); s0[7] = (short)f2bf(v1.w);
        s1[0] = (short)f2bf(v2.x); s1[1] = (short)f2bf(v2.y);
        s1[2] = (short)f2bf(v2.z); s1[3] = (short)f2bf(v2.w);
        s1[4] = (short)f2bf(v3.x); s1[5] = (short)f2bf(v3.y);
        s1[6] = (short)f2bf(v3.z); s1[7] = (short)f2bf(v3.w);
        *reinterpret_cast<short8*>(&Xs[r][c0]) = s0;
        *reinterpret_cast<short8*>(&Xs[r][c0 + 8]) = s1;
    }
    __syncthreads();

    int colz = w * 16 + ml;
    f32x4 acc3[4];
#pragma unroll
    for (int mt = 0; mt < 4; mt++) acc3[mt] = (f32x4){0.f, 0.f, 0.f, 0.f};
#pragma unroll
    for (int kb = 0; kb < 2; kb++) {
        short8 bg = *reinterpret_cast<const short8*>(&Gb[(w * 16 + ml) * 64 + kb * 32 + kg * 8]);
        short8 bk = *reinterpret_cast<const short8*>(&Kb[(w * 16 + ml) * 64 + kb * 32 + kg * 8]);
#pragma unroll
        for (int mt = 0; mt < 4; mt++) {
            short8 az = *reinterpret_cast<const short8*>(
                &zstg[(size_t)(row0 + mt * 16 + ml) * 64 + kb * 32 + kg * 8]);
            acc3[mt] = __builtin_amdgcn_mfma_f32_16x16x32_bf16(az, bg, acc3[mt], 0, 0, 0);
            short8 ax = *reinterpret_cast<const short8*>(&Xs[mt * 16 + ml][kb * 32 + kg * 8]);
            acc3[mt] = __builtin_amdgcn_mfma_f32_16x16x32_bf16(ax, bk, acc3[mt], 0, 0, 0);
        }
    }
#pragma unroll
    for (int mt = 0; mt < 4; mt++)
#pragma unroll
        for (int i = 0; i < 4; i++)
            Cs[mt * 16 + kg * 4 + i][colz] = f2bf(acc3[mt][i]);
    __syncthreads();

    {   // coalesced cbuf store
        int r = tid >> 2, c0 = (tid & 3) * 16;
        short8 s0 = *reinterpret_cast<const short8*>(&Cs[r][c0]);
        short8 s1 = *reinterpret_cast<const short8*>(&Cs[r][c0 + 8]);
        *reinterpret_cast<short8*>(&cbuf[(size_t)(row0 + r) * 64 + c0]) = s0;
        *reinterpret_cast<short8*>(&cbuf[(size_t)(row0 + r) * 64 + c0 + 8]) = s1;
    }

    {   // phase-A local scan: wave w scans chunk rows [16w,16w+16), zero init
        int j = lane;
        float m[64];
        load_mrow(Mw, j, m);
        unsigned short cv[16];
#pragma unroll
        for (int t = 0; t < 16; t++) cv[t] = Cs[w * 16 + t][j];
        float z = bf2f(cv[0]);
#pragma unroll
        for (int t = 1; t < 16; t++) z = matvec_rl(m, z, bf2f(cv[t]));
        int b = row0 >> 9;
        int chunk = ((row0 & 511) >> 4) + w;        // 0..31
        if (chunk != 31)
            Pbuf[((size_t)b * 32 + chunk + 1) * 64 + j] = z;
    }
}

// ---------------------------------------------------------------------------
// kchain : per batch, P[0]=0 ; P[c] = f[c-1] + M16 P[c-1]  (in-place, prefetch)
// ---------------------------------------------------------------------------
__global__ __launch_bounds__(64) void kchain(const float* __restrict__ M16w,
                                             float* __restrict__ Pbuf) {
    int b = blockIdx.x, j = threadIdx.x;
    float m[64];
    load_mrow(M16w, j, m);
    float* P = Pbuf + (size_t)b * 32 * 64;
    float fnext = P[64 + j];
    P[j] = 0.f;                                     // P[0]
    float z = 0.f;
    for (int c = 1; c < 32; c++) {
        float f = fnext;
        if (c < 31) fnext = P[(c + 1) * 64 + j];
        z = matvec_rl(m, z, f);
        P[c * 64 + j] = z;
    }
}

// ---------------------------------------------------------------------------
// kdec : phase-C chunk scans -> decoder GEMMs -> x_recon
// ---------------------------------------------------------------------------
__global__ __launch_bounds__(256) void kdec(float* __restrict__ xr,
                                            const float* __restrict__ db1,
                                            const float* __restrict__ db2,
                                            const unsigned short* __restrict__ d1t,
                                            const unsigned short* __restrict__ d2t,
                                            const float* __restrict__ Mw,
                                            const float* __restrict__ Pbuf,
                                            const unsigned short* __restrict__ cbuf) {
    __shared__ unsigned short Zs[64][72];
    __shared__ unsigned short Hs[64][264];
    int row0 = blockIdx.x * 64;
    int tid = threadIdx.x;
    int lane = tid & 63, w = tid >> 6;
    int ml = lane & 15, kg = lane >> 4;

    {   // phase-C scan
        int j = lane;
        int b = row0 >> 9;
        int chunk = ((row0 & 511) >> 4) + w;
        float m[64];
        load_mrow(Mw, j, m);
        float z = Pbuf[((size_t)b * 32 + chunk) * 64 + j];
        const unsigned short* cb = cbuf + ((size_t)row0 + w * 16) * 64;
        unsigned short cv[16];
#pragma unroll
        for (int t = 0; t < 16; t++) cv[t] = cb[t * 64 + j];
#pragma unroll
        for (int t = 0; t < 16; t++) {
            z = matvec_rl(m, z, bf2f(cv[t]));
            Zs[w * 16 + t][j] = f2bf(z);
        }
    }
    __syncthreads();

    short8 afr[4][2];
#pragma unroll
    for (int mt = 0; mt < 4; mt++)
#pragma unroll
        for (int kb = 0; kb < 2; kb++)
            afr[mt][kb] = *reinterpret_cast<const short8*>(&Zs[mt * 16 + ml][kb * 32 + kg * 8]);

#pragma unroll
    for (int q = 0; q < 4; q++) {
        int nt = w * 4 + q;
        f32x4 acc[4];
#pragma unroll
        for (int mt = 0; mt < 4; mt++) acc[mt] = (f32x4){0.f, 0.f, 0.f, 0.f};
#pragma unroll
        for (int kb = 0; kb < 2; kb++) {
            short8 bfr = *reinterpret_cast<const short8*>(&d1t[(nt * 16 + ml) * 64 + kb * 32 + kg * 8]);
#pragma unroll
            for (int mt = 0; mt < 4; mt++)
                acc[mt] = __builtin_amdgcn_mfma_f32_16x16x32_bf16(afr[mt][kb], bfr, acc[mt], 0, 0, 0);
        }
        float bias = db1[nt * 16 + ml];
#pragma unroll
        for (int mt = 0; mt < 4; mt++)
#pragma unroll
            for (int i = 0; i < 4; i++) {
                float v = acc[mt][i] + bias;
                v = v > 0.f ? v : 0.f;
                Hs[mt * 16 + kg * 4 + i][nt * 16 + ml] = f2bf(v);
            }
    }
    __syncthreads();

    f32x4 acc2[4];
#pragma unroll
    for (int mt = 0; mt < 4; mt++) acc2[mt] = (f32x4){0.f, 0.f, 0.f, 0.f};
#pragma unroll
    for (int kb = 0; kb < 8; kb++) {
        short8 bfr = *reinterpret_cast<const short8*>(&d2t[(w * 16 + ml) * 256 + kb * 32 + kg * 8]);
#pragma unroll
        for (int mt = 0; mt < 4; mt++) {
            short8 a2 = *reinterpret_cast<const short8*>(&Hs[mt * 16 + ml][kb * 32 + kg * 8]);
            acc2[mt] = __builtin_amdgcn_mfma_f32_16x16x32_bf16(a2, bfr, acc2[mt], 0, 0, 0);
        }
    }
    float bias2 = db2[w * 16 + ml];
#pragma unroll
    for (int mt = 0; mt < 4; mt++)
#pragma unroll
        for (int i = 0; i < 4; i++) {
            int r = mt * 16 + kg * 4 + i;
            float v = acc2[mt][i] + bias2;
            float s = 1.f / (1.f + expf(-v));
            xr[(size_t)(row0 + r) * 64 + w * 16 + ml] = s;
        }
}

// ---------------------------------------------------------------------------
extern "C" void kernel_launch(void* const* d_in, const int* in_sizes, int n_in,
                              void* d_out, int out_size, void* d_ws, size_t ws_size,
                              hipStream_t stream) {
    (void)in_sizes; (void)n_in; (void)out_size; (void)ws_size;
    const float* x      = (const float*)d_in[0];
    const float* eps    = (const float*)d_in[1];
    const float* enc_w1 = (const float*)d_in[2];
    const float* enc_b1 = (const float*)d_in[3];
    const float* enc_w2 = (const float*)d_in[4];
    const float* enc_b2 = (const float*)d_in[5];
    const float* dec_w1 = (const float*)d_in[6];
    const float* dec_b1 = (const float*)d_in[7];
    const float* dec_w2 = (const float*)d_in[8];
    const float* dec_b2 = (const float*)d_in[9];
    const float* Ain    = (const float*)d_in[10];
    const float* Qin    = (const float*)d_in[11];
    const float* Hin    = (const float*)d_in[12];
    const float* Rin    = (const float*)d_in[13];

    float* out   = (float*)d_out;
    float* xrec  = out;                              // x_recon; zstg staging
    float* zmean = out + OUTSEG;
    float* zlogv = out + 2 * OUTSEG;
    unsigned short* zstg = (unsigned short*)xrec;    // 16.8 MB of 33.5 MB region

    char* ws = (char*)d_ws;
    float*          Mw   = (float*)(ws);                    // 16 KB
    float*          M16w = (float*)(ws + 16384);            // 16 KB
    unsigned short* Gb   = (unsigned short*)(ws + 131072);  // 8 KB
    unsigned short* Kb   = (unsigned short*)(ws + 139264);  // 8 KB
    unsigned short* w1t  = (unsigned short*)(ws + 147456);  // 32 KB
    unsigned short* w2t  = (unsigned short*)(ws + 180224);  // 64 KB
    unsigned short* d1t  = (unsigned short*)(ws + 245760);  // 32 KB
    unsigned short* d2t  = (unsigned short*)(ws + 278528);  // 32 KB
    float*          Pbuf = (float*)(ws + 311296);           // 2 MB
    unsigned short* cbuf = (unsigned short*)(ws + 2408448); // 16.8 MB (end ~18.3MB)

    hipLaunchKernelGGL(ktr, dim3(20), dim3(256), 0, stream,
                       enc_w1, enc_w2, dec_w1, dec_w2, w1t, w2t, d1t, d2t);
    hipLaunchKernelGGL(kenc1, dim3(2048), dim3(256), 0, stream,
                       x, eps, enc_b1, enc_b2, w1t, w2t, zstg, zmean, zlogv);
    hipLaunchKernelGGL(kmc, dim3(1), dim3(256), 0, stream,
                       Ain, Qin, Hin, Rin, Mw, M16w, Gb, Kb);
    hipLaunchKernelGGL(kenc2, dim3(2048), dim3(256), 0, stream,
                       x, zstg, Gb, Kb, Mw, cbuf, Pbuf);
    hipLaunchKernelGGL(kchain, dim3(256), dim3(64), 0, stream, M16w, Pbuf);
    hipLaunchKernelGGL(kdec, dim3(2048), dim3(256), 0, stream,
                       xrec, dec_b1, dec_b2, d1t, d2t, Mw, Pbuf, cbuf);
}

// Round 7
// 471.988 us; speedup vs baseline: 2.1069x; 1.3143x over previous
//
#include <hip/hip_runtime.h>
#include <hip/hip_bf16.h>

// ---------------------------------------------------------------------------
// KalmanVAE: B=256, S=512, D=64, L=64, HID=256
// out = [x_recon | z_mean | z_logvar], each 131072*64 fp32
//
// z_up_t = M z_{t-1} + c_t,  M = (I-K Hm) A,  c_t = G z_t + K x_t, G = I-K Hm
// Kernels:
//   ktr   : 20 blocks, bf16 transposed weight copies.
//   kenc1 : encoder GEMMs + reparam -> zstg bf16 (out region 0), zmean/zlogv.
//   kmc   : 1 block. LDS broadcast-b128 matmuls (4 waves) + single-wave GJ
//           with STATIC register indices (cndmask row-extract + dynamic-lane
//           __shfl column broadcast; outer k loop stays dynamic -> no scratch).
//   kenc2 : c = z@G^T + x@K^T -> cbuf bf16 + phase-A chunk scans -> Pbuf.
//   kchain: per-batch chunk prefix with M^16 (prefetched).
//   kdec  : phase-C chunk scans -> decoder GEMMs -> x_recon.
// ---------------------------------------------------------------------------

typedef short short8 __attribute__((ext_vector_type(8)));
typedef float f32x4 __attribute__((ext_vector_type(4)));

#define OUTSEG 8388608   // 131072*64

__device__ __forceinline__ unsigned short f2bf(float f) {
    unsigned int u = __builtin_bit_cast(unsigned int, f);
    u += 0x7fffu + ((u >> 16) & 1u);   // RNE
    return (unsigned short)(u >> 16);
}
__device__ __forceinline__ float bf2f(unsigned short h) {
    unsigned int u = ((unsigned int)h) << 16;
    return __builtin_bit_cast(float, u);
}
__device__ __forceinline__ float rlf(float v, int l) {
    return __builtin_bit_cast(float, __builtin_amdgcn_readlane(__builtin_bit_cast(int, v), l));
}
// z_new[j] = c[j] + sum_k m[k] * z[k]   (m = row j of M, one wave, no barriers)
__device__ __forceinline__ float matvec_rl(const float* m, float z, float c) {
    float a0 = c, a1 = 0.f, a2 = 0.f, a3 = 0.f;
#pragma unroll
    for (int k = 0; k < 64; k += 4) {
        a0 = fmaf(m[k + 0], rlf(z, k + 0), a0);
        a1 = fmaf(m[k + 1], rlf(z, k + 1), a1);
        a2 = fmaf(m[k + 2], rlf(z, k + 2), a2);
        a3 = fmaf(m[k + 3], rlf(z, k + 3), a3);
    }
    return (a0 + a1) + (a2 + a3);
}
__device__ __forceinline__ void load_mrow(const float* Mp, int j, float* m) {
#pragma unroll
    for (int q = 0; q < 16; q++) {
        float4 v = *reinterpret_cast<const float4*>(&Mp[j * 64 + q * 4]);
        m[q * 4 + 0] = v.x; m[q * 4 + 1] = v.y;
        m[q * 4 + 2] = v.z; m[q * 4 + 3] = v.w;
    }
}

// ---------------------------------------------------------------------------
// ktr : weight transposes (bf16), 20 blocks x 256 threads
// ---------------------------------------------------------------------------
__device__ void tr_tile(const float* src, int sld, unsigned short* dst, int dld,
                        int r0, int c0, int tid, float* LT) {
    int rr = tid >> 2, q = tid & 3;
#pragma unroll
    for (int u = 0; u < 4; u++) {
        float4 v = *reinterpret_cast<const float4*>(
            &src[(size_t)(r0 + rr) * sld + c0 + q * 16 + u * 4]);
        LT[rr * 65 + q * 16 + u * 4 + 0] = v.x;
        LT[rr * 65 + q * 16 + u * 4 + 1] = v.y;
        LT[rr * 65 + q * 16 + u * 4 + 2] = v.z;
        LT[rr * 65 + q * 16 + u * 4 + 3] = v.w;
    }
    __syncthreads();
    short8 s0, s1;
#pragma unroll
    for (int u = 0; u < 8; u++) s0[u] = (short)f2bf(LT[(q * 16 + u) * 65 + rr]);
#pragma unroll
    for (int u = 0; u < 8; u++) s1[u] = (short)f2bf(LT[(q * 16 + 8 + u) * 65 + rr]);
    *reinterpret_cast<short8*>(&dst[(size_t)(c0 + rr) * dld + r0 + q * 16]) = s0;
    *reinterpret_cast<short8*>(&dst[(size_t)(c0 + rr) * dld + r0 + q * 16 + 8]) = s1;
}

__global__ __launch_bounds__(256) void ktr(
    const float* __restrict__ ew1, const float* __restrict__ ew2,
    const float* __restrict__ dw1, const float* __restrict__ dw2,
    unsigned short* __restrict__ w1t, unsigned short* __restrict__ w2t,
    unsigned short* __restrict__ d1t, unsigned short* __restrict__ d2t) {
    __shared__ float La[64 * 65];
    int tid = threadIdx.x;
    int t = blockIdx.x;
    const float* src; unsigned short* dst; int sld, dld, r0, c0;
    if (t < 4)       { src = ew1; dst = w1t; sld = 256; dld = 64;  r0 = 0;             c0 = t * 64; }
    else if (t < 12) { int i = t - 4;  src = ew2; dst = w2t; sld = 128; dld = 256; r0 = (i >> 1) * 64; c0 = (i & 1) * 64; }
    else if (t < 16) { int i = t - 12; src = dw1; dst = d1t; sld = 256; dld = 64;  r0 = 0;             c0 = i * 64; }
    else             { int i = t - 16; src = dw2; dst = d2t; sld = 64;  dld = 256; r0 = i * 64;        c0 = 0; }
    tr_tile(src, sld, dst, dld, r0, c0, tid, La);
}

// ---------------------------------------------------------------------------
// kmc : matrix chain, 1 block x 256 threads. LDS pitch 68 floats (16B-align).
// ---------------------------------------------------------------------------
__device__ __forceinline__ void stage4(const float* __restrict__ g, float* L, int tid) {
#pragma unroll
    for (int n = 0; n < 16; n++) {
        int idx = tid + n * 256;
        L[(idx >> 6) * 68 + (idx & 63)] = g[idx];
    }
}

// C = A@B (mode 0) ; C = A@B + Dg (mode 1, Dg global pitch 64) ; C = I - A@B (2)
// A-row in regs (b128), B via wave-uniform broadcast b128. Barrier at end.
__device__ __forceinline__ void mml(const float* pa, const float* pb, float* pc,
                                    int mode, const float* __restrict__ gd,
                                    float* __restrict__ gout,
                                    unsigned short* __restrict__ bout, int tid) {
    int i = tid & 63, j0 = (tid >> 6) * 16;
    float a[64];
#pragma unroll
    for (int u = 0; u < 16; u++) {
        float4 v = *reinterpret_cast<const float4*>(&pa[i * 68 + u * 4]);
        a[u * 4 + 0] = v.x; a[u * 4 + 1] = v.y;
        a[u * 4 + 2] = v.z; a[u * 4 + 3] = v.w;
    }
    float acc[4][4];
#pragma unroll
    for (int q = 0; q < 4; q++)
#pragma unroll
        for (int e = 0; e < 4; e++) acc[q][e] = 0.f;
#pragma unroll 4
    for (int k = 0; k < 64; k++) {
        float ak = a[k];
#pragma unroll
        for (int q = 0; q < 4; q++) {
            float4 b = *reinterpret_cast<const float4*>(&pb[k * 68 + j0 + q * 4]);
            acc[q][0] = fmaf(ak, b.x, acc[q][0]);
            acc[q][1] = fmaf(ak, b.y, acc[q][1]);
            acc[q][2] = fmaf(ak, b.z, acc[q][2]);
            acc[q][3] = fmaf(ak, b.w, acc[q][3]);
        }
    }
#pragma unroll
    for (int q = 0; q < 4; q++) {
        int j = j0 + q * 4;
        if (mode == 1) {
            float4 d = *reinterpret_cast<const float4*>(&gd[i * 64 + j]);
            acc[q][0] += d.x; acc[q][1] += d.y; acc[q][2] += d.z; acc[q][3] += d.w;
        } else if (mode == 2) {
#pragma unroll
            for (int e = 0; e < 4; e++)
                acc[q][e] = ((i == j + e) ? 1.f : 0.f) - acc[q][e];
        }
        float4 v = {acc[q][0], acc[q][1], acc[q][2], acc[q][3]};
        *reinterpret_cast<float4*>(&pc[i * 68 + j]) = v;
        if (gout) *reinterpret_cast<float4*>(&gout[i * 64 + j]) = v;
        if (bout) {
            bout[i * 64 + j + 0] = f2bf(v.x);
            bout[i * 64 + j + 1] = f2bf(v.y);
            bout[i * 64 + j + 2] = f2bf(v.z);
            bout[i * 64 + j + 3] = f2bf(v.w);
        }
    }
    __syncthreads();
}

__global__ __launch_bounds__(256) void kmc(
    const float* __restrict__ Ain, const float* __restrict__ Qin,
    const float* __restrict__ Hin, const float* __restrict__ Rin,
    float* __restrict__ Mw, float* __restrict__ M16w,
    unsigned short* __restrict__ Gb, unsigned short* __restrict__ Kb) {
    __shared__ __align__(16) float LB[4 * 64 * 68];   // 69632 B
    float* B0 = LB;                 // A      -> M2 -> M16
    float* B1 = LB + 4352;          // Q -> S -> G  -> M4
    float* B2 = LB + 8704;          // AQ -> K -> M -> M8
    float* B3 = LB + 13056;         // Hm
    int tid = threadIdx.x;

    stage4(Ain, B0, tid);
    stage4(Qin, B1, tid);
    stage4(Hin, B3, tid);
    __syncthreads();

    mml(B0, B1, B2, 0, nullptr, nullptr, nullptr, tid);   // B2 = AQ
    mml(B3, B2, B1, 1, Rin,     nullptr, nullptr, tid);   // B1 = S = Hm@AQ + R

    // ---- single-wave GJ, static register indices only ----
    // lane j holds column j of [S^T | AQ^T] = (row j of S | row j of AQ).
    // Per pivot k (k DYNAMIC, loop not unrolled):
    //   aug[k][j] (own r[k]) -> cndmask select over unrolled i
    //   aug[i][k] (column k) -> __shfl(r[i], k), i static
    if (tid < 64) {
        int j = tid;
        float r[64], q[64];
#pragma unroll
        for (int u = 0; u < 16; u++) {
            float4 v = *reinterpret_cast<const float4*>(&B1[j * 68 + u * 4]);
            r[u * 4 + 0] = v.x; r[u * 4 + 1] = v.y;
            r[u * 4 + 2] = v.z; r[u * 4 + 3] = v.w;
            float4 w = *reinterpret_cast<const float4*>(&B2[j * 68 + u * 4]);
            q[u * 4 + 0] = w.x; q[u * 4 + 1] = w.y;
            q[u * 4 + 2] = w.z; q[u * 4 + 3] = w.w;
        }
#pragma unroll 1
        for (int k = 0; k < 64; k++) {
            float rowkL = 0.f, rowkR = 0.f;     // this lane's aug[k][j]
#pragma unroll
            for (int i = 0; i < 64; i++) {
                rowkL = (i == k) ? r[i] : rowkL;
                rowkR = (i == k) ? q[i] : rowkR;
            }
            float pv = __shfl(rowkL, k);        // aug[k][k]
            float rp = 1.0f / pv;
            float tL = rowkL * rp;              // scaled pivot row elem
            float tR = rowkR * rp;
#pragma unroll
            for (int i = 0; i < 64; i++) {
                float mi = __shfl(r[i], k);     // aug[i][k] (pre-update)
                float rn = fmaf(-mi, tL, r[i]);
                float qn = fmaf(-mi, tR, q[i]);
                r[i] = (i == k) ? tL : rn;
                q[i] = (i == k) ? tR : qn;
            }
        }
        // lane j now holds K row j in q[]. Write K -> B2 (pitch 68) + Kb bf16.
#pragma unroll
        for (int u = 0; u < 16; u++) {
            float4 v = {q[u * 4], q[u * 4 + 1], q[u * 4 + 2], q[u * 4 + 3]};
            *reinterpret_cast<float4*>(&B2[j * 68 + u * 4]) = v;
        }
#pragma unroll
        for (int u = 0; u < 8; u++) {
            short8 s;
#pragma unroll
            for (int e = 0; e < 8; e++) s[e] = (short)f2bf(q[u * 8 + e]);
            *reinterpret_cast<short8*>(&Kb[j * 64 + u * 8]) = s;
        }
    }
    __syncthreads();

    mml(B2, B3, B1, 2, nullptr, nullptr, Gb, tid);        // B1 = G = I - K@Hm
    mml(B1, B0, B2, 0, nullptr, Mw, nullptr, tid);        // B2 = M = G@A
    mml(B2, B2, B0, 0, nullptr, nullptr, nullptr, tid);   // B0 = M^2
    mml(B0, B0, B1, 0, nullptr, nullptr, nullptr, tid);   // B1 = M^4
    mml(B1, B1, B2, 0, nullptr, nullptr, nullptr, tid);   // B2 = M^8
    mml(B2, B2, B0, 0, nullptr, M16w, nullptr, tid);      // B0 = M^16 (+global)
}

// ---------------------------------------------------------------------------
// kenc1 : encoder only, 64 rows/block, grid 2048.
//         GEMM1 -> relu -> GEMM2 -> reparam -> zmean/zlogv out, z bf16 -> zstg
// ---------------------------------------------------------------------------
__global__ __launch_bounds__(256) void kenc1(
    const float* __restrict__ x, const float* __restrict__ eps,
    const float* __restrict__ b1, const float* __restrict__ b2,
    const unsigned short* __restrict__ w1t, const unsigned short* __restrict__ w2t,
    unsigned short* __restrict__ zstg, float* __restrict__ zmean,
    float* __restrict__ zlogv) {
    __shared__ unsigned short Xs[64][72];
    __shared__ unsigned short Hs[64][264];
    __shared__ unsigned short Zs[64][72];
    int row0 = blockIdx.x * 64;
    int tid = threadIdx.x;
    int lane = tid & 63, w = tid >> 6;
    int ml = lane & 15, kg = lane >> 4;

    {   // stage X tile -> bf16 LDS
        int r = tid >> 2, c0 = (tid & 3) * 16;
        const float4* xp = reinterpret_cast<const float4*>(&x[(size_t)(row0 + r) * 64 + c0]);
        float4 v0 = xp[0], v1 = xp[1], v2 = xp[2], v3 = xp[3];
        short8 s0, s1;
        s0[0] = (short)f2bf(v0.x); s0[1] = (short)f2bf(v0.y);
        s0[2] = (short)f2bf(v0.z); s0[3] = (short)f2bf(v0.w);
        s0[4] = (short)f2bf(v1.x); s0[5] = (short)f2bf(v1.y);
        s0[6] = (short)f2bf(v1.z); s0[7] = (short)f2bf(v1.w);
        s1[0] = (short)f2bf(v2.x); s1[1] = (short)f2bf(v2.y);
        s1[2] = (short)f2bf(v2.z); s1[3] = (short)f2bf(v2.w);
        s1[4] = (short)f2bf(v3.x); s1[5] = (short)f2bf(v3.y);
        s1[6] = (short)f2bf(v3.z); s1[7] = (short)f2bf(v3.w);
        *reinterpret_cast<short8*>(&Xs[r][c0]) = s0;
        *reinterpret_cast<short8*>(&Xs[r][c0 + 8]) = s1;
    }
    __syncthreads();

    short8 afr[4][2];
#pragma unroll
    for (int mt = 0; mt < 4; mt++)
#pragma unroll
        for (int kb = 0; kb < 2; kb++)
            afr[mt][kb] = *reinterpret_cast<const short8*>(&Xs[mt * 16 + ml][kb * 32 + kg * 8]);

    // GEMM1: wave w -> n-tiles 4w..4w+3 of H[64,256]
#pragma unroll
    for (int q = 0; q < 4; q++) {
        int nt = w * 4 + q;
        f32x4 acc[4];
#pragma unroll
        for (int mt = 0; mt < 4; mt++) acc[mt] = (f32x4){0.f, 0.f, 0.f, 0.f};
#pragma unroll
        for (int kb = 0; kb < 2; kb++) {
            short8 bfr = *reinterpret_cast<const short8*>(&w1t[(nt * 16 + ml) * 64 + kb * 32 + kg * 8]);
#pragma unroll
            for (int mt = 0; mt < 4; mt++)
                acc[mt] = __builtin_amdgcn_mfma_f32_16x16x32_bf16(afr[mt][kb], bfr, acc[mt], 0, 0, 0);
        }
        float bias = b1[nt * 16 + ml];
#pragma unroll
        for (int mt = 0; mt < 4; mt++)
#pragma unroll
            for (int i = 0; i < 4; i++) {
                float v = acc[mt][i] + bias;
                v = v > 0.f ? v : 0.f;
                Hs[mt * 16 + kg * 4 + i][nt * 16 + ml] = f2bf(v);
            }
    }
    __syncthreads();

    // GEMM2: wave w -> n-tiles {w, w+4} of ML[64,128]
    f32x4 acc2[2][4];
#pragma unroll
    for (int p = 0; p < 2; p++)
#pragma unroll
        for (int mt = 0; mt < 4; mt++) acc2[p][mt] = (f32x4){0.f, 0.f, 0.f, 0.f};
#pragma unroll
    for (int kb = 0; kb < 8; kb++) {
        short8 a2[4];
#pragma unroll
        for (int mt = 0; mt < 4; mt++)
            a2[mt] = *reinterpret_cast<const short8*>(&Hs[mt * 16 + ml][kb * 32 + kg * 8]);
#pragma unroll
        for (int p = 0; p < 2; p++) {
            int nt = w + 4 * p;
            short8 bfr = *reinterpret_cast<const short8*>(&w2t[(nt * 16 + ml) * 256 + kb * 32 + kg * 8]);
#pragma unroll
            for (int mt = 0; mt < 4; mt++)
                acc2[p][mt] = __builtin_amdgcn_mfma_f32_16x16x32_bf16(a2[mt], bfr, acc2[p][mt], 0, 0, 0);
        }
    }
    int colz = w * 16 + ml;
    float bm = b2[colz], bl = b2[64 + colz];
#pragma unroll
    for (int mt = 0; mt < 4; mt++)
#pragma unroll
        for (int i = 0; i < 4; i++) {
            int r = mt * 16 + kg * 4 + i;
            size_t grow = (size_t)(row0 + r);
            float zm = acc2[0][mt][i] + bm;
            float zl = acc2[1][mt][i] + bl;
            zmean[grow * 64 + colz] = zm;
            zlogv[grow * 64 + colz] = zl;
            float zz = zm + eps[grow * 64 + colz] * expf(0.5f * zl);
            Zs[r][colz] = f2bf(zz);
        }
    __syncthreads();

    {   // coalesced zstg store
        int r = tid >> 2, c0 = (tid & 3) * 16;
        short8 s0 = *reinterpret_cast<const short8*>(&Zs[r][c0]);
        short8 s1 = *reinterpret_cast<const short8*>(&Zs[r][c0 + 8]);
        *reinterpret_cast<short8*>(&zstg[(size_t)(row0 + r) * 64 + c0]) = s0;
        *reinterpret_cast<short8*>(&zstg[(size_t)(row0 + r) * 64 + c0 + 8]) = s1;
    }
}

// ---------------------------------------------------------------------------
// kenc2 : c = z@G^T + x@K^T -> cbuf bf16 + phase-A chunk scans -> Pbuf
// ---------------------------------------------------------------------------
__global__ __launch_bounds__(256) void kenc2(
    const float* __restrict__ x, const unsigned short* __restrict__ zstg,
    const unsigned short* __restrict__ Gb, const unsigned short* __restrict__ Kb,
    const float* __restrict__ Mw, unsigned short* __restrict__ cbuf,
    float* __restrict__ Pbuf) {
    __shared__ unsigned short Xs[64][72];
    __shared__ unsigned short Cs[64][72];
    int row0 = blockIdx.x * 64;
    int tid = threadIdx.x;
    int lane = tid & 63, w = tid >> 6;
    int ml = lane & 15, kg = lane >> 4;

    {   // stage X tile -> bf16 LDS
        int r = tid >> 2, c0 = (tid & 3) * 16;
        const float4* xp = reinterpret_cast<const float4*>(&x[(size_t)(row0 + r) * 64 + c0]);
        float4 v0 = xp[0], v1 = xp[1], v2 = xp[2], v3 = xp[3];
        short8 s0, s1;
        s0[0] = (short)f2bf(v0.x); s0[1] = (short)f2bf(v0.y);
        s0[2] = (short)f2bf(v0.z); s0[3] = (short)f2bf(v0.w);
        s0[4] = (short)f2bf(v1.x); s0[5] = (short)f2bf(v1.y);
        s0[6] = (short)f2bf(v1.z); s0[7] = (short)f2bf(v1.w);
        s1[0] = (short)f2bf(v2.x); s1[1] = (short)f2bf(v2.y);
        s1[2] = (short)f2bf(v2.z); s1[3] = (short)f2bf(v2.w);
        s1[4] = (short)f2bf(v3.x); s1[5] = (short)f2bf(v3.y);
        s1[6] = (short)f2bf(v3.z); s1[7] = (short)f2bf(v3.w);
        *reinterpret_cast<short8*>(&Xs[r][c0]) = s0;
        *reinterpret_cast<short8*>(&Xs[r][c0 + 8]) = s1;
    }
    __syncthreads();

    int colz = w * 16 + ml;
    f32x4 acc3[4];
#pragma unroll
    for (int mt = 0; mt < 4; mt++) acc3[mt] = (f32x4){0.f, 0.f, 0.f, 0.f};
#pragma unroll
    for (int kb = 0; kb < 2; kb++) {
        short8 bg = *reinterpret_cast<const short8*>(&Gb[(w * 16 + ml) * 64 + kb * 32 + kg * 8]);
        short8 bk = *reinterpret_cast<const short8*>(&Kb[(w * 16 + ml) * 64 + kb * 32 + kg * 8]);
#pragma unroll
        for (int mt = 0; mt < 4; mt++) {
            short8 az = *reinterpret_cast<const short8*>(
                &zstg[(size_t)(row0 + mt * 16 + ml) * 64 + kb * 32 + kg * 8]);
            acc3[mt] = __builtin_amdgcn_mfma_f32_16x16x32_bf16(az, bg, acc3[mt], 0, 0, 0);
            short8 ax = *reinterpret_cast<const short8*>(&Xs[mt * 16 + ml][kb * 32 + kg * 8]);
            acc3[mt] = __builtin_amdgcn_mfma_f32_16x16x32_bf16(ax, bk, acc3[mt], 0, 0, 0);
        }
    }
#pragma unroll
    for (int mt = 0; mt < 4; mt++)
#pragma unroll
        for (int i = 0; i < 4; i++)
            Cs[mt * 16 + kg * 4 + i][colz] = f2bf(acc3[mt][i]);
    __syncthreads();

    {   // coalesced cbuf store
        int r = tid >> 2, c0 = (tid & 3) * 16;
        short8 s0 = *reinterpret_cast<const short8*>(&Cs[r][c0]);
        short8 s1 = *reinterpret_cast<const short8*>(&Cs[r][c0 + 8]);
        *reinterpret_cast<short8*>(&cbuf[(size_t)(row0 + r) * 64 + c0]) = s0;
        *reinterpret_cast<short8*>(&cbuf[(size_t)(row0 + r) * 64 + c0 + 8]) = s1;
    }

    {   // phase-A local scan: wave w scans chunk rows [16w,16w+16), zero init
        int j = lane;
        float m[64];
        load_mrow(Mw, j, m);
        unsigned short cv[16];
#pragma unroll
        for (int t = 0; t < 16; t++) cv[t] = Cs[w * 16 + t][j];
        float z = bf2f(cv[0]);
#pragma unroll
        for (int t = 1; t < 16; t++) z = matvec_rl(m, z, bf2f(cv[t]));
        int b = row0 >> 9;
        int chunk = ((row0 & 511) >> 4) + w;        // 0..31
        if (chunk != 31)
            Pbuf[((size_t)b * 32 + chunk + 1) * 64 + j] = z;
    }
}

// ---------------------------------------------------------------------------
// kchain : per batch, P[0]=0 ; P[c] = f[c-1] + M16 P[c-1]  (in-place, prefetch)
// ---------------------------------------------------------------------------
__global__ __launch_bounds__(64) void kchain(const float* __restrict__ M16w,
                                             float* __restrict__ Pbuf) {
    int b = blockIdx.x, j = threadIdx.x;
    float m[64];
    load_mrow(M16w, j, m);
    float* P = Pbuf + (size_t)b * 32 * 64;
    float fnext = P[64 + j];
    P[j] = 0.f;                                     // P[0]
    float z = 0.f;
    for (int c = 1; c < 32; c++) {
        float f = fnext;
        if (c < 31) fnext = P[(c + 1) * 64 + j];
        z = matvec_rl(m, z, f);
        P[c * 64 + j] = z;
    }
}

// ---------------------------------------------------------------------------
// kdec : phase-C chunk scans -> decoder GEMMs -> x_recon
// ---------------------------------------------------------------------------
__global__ __launch_bounds__(256) void kdec(float* __restrict__ xr,
                                            const float* __restrict__ db1,
                                            const float* __restrict__ db2,
                                            const unsigned short* __restrict__ d1t,
                                            const unsigned short* __restrict__ d2t,
                                            const float* __restrict__ Mw,
                                            const float* __restrict__ Pbuf,
                                            const unsigned short* __restrict__ cbuf) {
    __shared__ unsigned short Zs[64][72];
    __shared__ unsigned short Hs[64][264];
    int row0 = blockIdx.x * 64;
    int tid = threadIdx.x;
    int lane = tid & 63, w = tid >> 6;
    int ml = lane & 15, kg = lane >> 4;

    {   // phase-C scan
        int j = lane;
        int b = row0 >> 9;
        int chunk = ((row0 & 511) >> 4) + w;
        float m[64];
        load_mrow(Mw, j, m);
        float z = Pbuf[((size_t)b * 32 + chunk) * 64 + j];
        const unsigned short* cb = cbuf + ((size_t)row0 + w * 16) * 64;
        unsigned short cv[16];
#pragma unroll
        for (int t = 0; t < 16; t++) cv[t] = cb[t * 64 + j];
#pragma unroll
        for (int t = 0; t < 16; t++) {
            z = matvec_rl(m, z, bf2f(cv[t]));
            Zs[w * 16 + t][j] = f2bf(z);
        }
    }
    __syncthreads();

    short8 afr[4][2];
#pragma unroll
    for (int mt = 0; mt < 4; mt++)
#pragma unroll
        for (int kb = 0; kb < 2; kb++)
            afr[mt][kb] = *reinterpret_cast<const short8*>(&Zs[mt * 16 + ml][kb * 32 + kg * 8]);

#pragma unroll
    for (int q = 0; q < 4; q++) {
        int nt = w * 4 + q;
        f32x4 acc[4];
#pragma unroll
        for (int mt = 0; mt < 4; mt++) acc[mt] = (f32x4){0.f, 0.f, 0.f, 0.f};
#pragma unroll
        for (int kb = 0; kb < 2; kb++) {
            short8 bfr = *reinterpret_cast<const short8*>(&d1t[(nt * 16 + ml) * 64 + kb * 32 + kg * 8]);
#pragma unroll
            for (int mt = 0; mt < 4; mt++)
                acc[mt] = __builtin_amdgcn_mfma_f32_16x16x32_bf16(afr[mt][kb], bfr, acc[mt], 0, 0, 0);
        }
        float bias = db1[nt * 16 + ml];
#pragma unroll
        for (int mt = 0; mt < 4; mt++)
#pragma unroll
            for (int i = 0; i < 4; i++) {
                float v = acc[mt][i] + bias;
                v = v > 0.f ? v : 0.f;
                Hs[mt * 16 + kg * 4 + i][nt * 16 + ml] = f2bf(v);
            }
    }
    __syncthreads();

    f32x4 acc2[4];
#pragma unroll
    for (int mt = 0; mt < 4; mt++) acc2[mt] = (f32x4){0.f, 0.f, 0.f, 0.f};
#pragma unroll
    for (int kb = 0; kb < 8; kb++) {
        short8 bfr = *reinterpret_cast<const short8*>(&d2t[(w * 16 + ml) * 256 + kb * 32 + kg * 8]);
#pragma unroll
        for (int mt = 0; mt < 4; mt++) {
            short8 a2 = *reinterpret_cast<const short8*>(&Hs[mt * 16 + ml][kb * 32 + kg * 8]);
            acc2[mt] = __builtin_amdgcn_mfma_f32_16x16x32_bf16(a2, bfr, acc2[mt], 0, 0, 0);
        }
    }
    float bias2 = db2[w * 16 + ml];
#pragma unroll
    for (int mt = 0; mt < 4; mt++)
#pragma unroll
        for (int i = 0; i < 4; i++) {
            int r = mt * 16 + kg * 4 + i;
            float v = acc2[mt][i] + bias2;
            float s = 1.f / (1.f + expf(-v));
            xr[(size_t)(row0 + r) * 64 + w * 16 + ml] = s;
        }
}

// ---------------------------------------------------------------------------
extern "C" void kernel_launch(void* const* d_in, const int* in_sizes, int n_in,
                              void* d_out, int out_size, void* d_ws, size_t ws_size,
                              hipStream_t stream) {
    (void)in_sizes; (void)n_in; (void)out_size; (void)ws_size;
    const float* x      = (const float*)d_in[0];
    const float* eps    = (const float*)d_in[1];
    const float* enc_w1 = (const float*)d_in[2];
    const float* enc_b1 = (const float*)d_in[3];
    const float* enc_w2 = (const float*)d_in[4];
    const float* enc_b2 = (const float*)d_in[5];
    const float* dec_w1 = (const float*)d_in[6];
    const float* dec_b1 = (const float*)d_in[7];
    const float* dec_w2 = (const float*)d_in[8];
    const float* dec_b2 = (const float*)d_in[9];
    const float* Ain    = (const float*)d_in[10];
    const float* Qin    = (const float*)d_in[11];
    const float* Hin    = (const float*)d_in[12];
    const float* Rin    = (const float*)d_in[13];

    float* out   = (float*)d_out;
    float* xrec  = out;                              // x_recon; zstg staging
    float* zmean = out + OUTSEG;
    float* zlogv = out + 2 * OUTSEG;
    unsigned short* zstg = (unsigned short*)xrec;    // 16.8 MB of 33.5 MB region

    char* ws = (char*)d_ws;
    float*          Mw   = (float*)(ws);                    // 16 KB
    float*          M16w = (float*)(ws + 16384);            // 16 KB
    unsigned short* Gb   = (unsigned short*)(ws + 131072);  // 8 KB
    unsigned short* Kb   = (unsigned short*)(ws + 139264);  // 8 KB
    unsigned short* w1t  = (unsigned short*)(ws + 147456);  // 32 KB
    unsigned short* w2t  = (unsigned short*)(ws + 180224);  // 64 KB
    unsigned short* d1t  = (unsigned short*)(ws + 245760);  // 32 KB
    unsigned short* d2t  = (unsigned short*)(ws + 278528);  // 32 KB
    float*          Pbuf = (float*)(ws + 311296);           // 2 MB
    unsigned short* cbuf = (unsigned short*)(ws + 2408448); // 16.8 MB (end ~18.3MB)

    hipLaunchKernelGGL(ktr, dim3(20), dim3(256), 0, stream,
                       enc_w1, enc_w2, dec_w1, dec_w2, w1t, w2t, d1t, d2t);
    hipLaunchKernelGGL(kenc1, dim3(2048), dim3(256), 0, stream,
                       x, eps, enc_b1, enc_b2, w1t, w2t, zstg, zmean, zlogv);
    hipLaunchKernelGGL(kmc, dim3(1), dim3(256), 0, stream,
                       Ain, Qin, Hin, Rin, Mw, M16w, Gb, Kb);
    hipLaunchKernelGGL(kenc2, dim3(2048), dim3(256), 0, stream,
                       x, zstg, Gb, Kb, Mw, cbuf, Pbuf);
    hipLaunchKernelGGL(kchain, dim3(256), dim3(64), 0, stream, M16w, Pbuf);
    hipLaunchKernelGGL(kdec, dim3(2048), dim3(256), 0, stream,
                       xrec, dec_b1, dec_b2, d1t, d2t, Mw, Pbuf, cbuf);
}